// Round 1
// baseline (1326.911 us; speedup 1.0000x reference)
//
#include <hip/hip_runtime.h>
#include <hip/hip_bf16.h>

#define B_ 32
#define S_ 4096
#define H_ 256
#define D_ 512

// tanh(x) = 1 - 2/(exp(2x)+1); __expf -> v_exp_f32 path, ~1e-6 rel err, robust at +-inf
__device__ __forceinline__ float fast_tanh(float x) {
    return 1.0f - 2.0f / (__expf(2.0f * x) + 1.0f);
}

// -------- kernel A: dec_feat[b][e] = sum_d s_t[b][d] * Ws_w[e][d] + Ws_b[e] --------
__global__ __launch_bounds__(512)
void decfeat_kernel(const float* __restrict__ h_dec, const float* __restrict__ c_dec,
                    const float* __restrict__ Ws_w, const float* __restrict__ Ws_b,
                    float* __restrict__ dec_feat) {
    int b = blockIdx.x;
    int e = threadIdx.x;              // 0..511
    __shared__ float st[D_];
    st[e] = (e < H_) ? h_dec[b * H_ + e] : c_dec[b * H_ + (e - H_)];
    __syncthreads();
    const float4* wr = reinterpret_cast<const float4*>(Ws_w + (size_t)e * D_);
    const float4* sv = reinterpret_cast<const float4*>(st);
    float acc = 0.f;
#pragma unroll 4
    for (int i = 0; i < D_ / 4; ++i) {
        float4 w = wr[i];
        float4 s = sv[i];
        acc += w.x * s.x + w.y * s.y + w.z * s.z + w.w * s.w;
    }
    dec_feat[b * D_ + e] = acc + Ws_b[e];
}

// -------- kernel A2: WhT[k][e] = Wh_w[e][k] (for coalesced weight loads in score_kernel)
__global__ __launch_bounds__(256)
void transpose_kernel(const float* __restrict__ Wh, float* __restrict__ WhT) {
    __shared__ float tile[32][33];
    int bx = blockIdx.x * 32;         // k-tile base (input col)
    int by = blockIdx.y * 32;         // e-tile base (input row)
    int tx = threadIdx.x;             // 0..31
    int ty = threadIdx.y;             // 0..7
#pragma unroll
    for (int j = 0; j < 32; j += 8)
        tile[ty + j][tx] = Wh[(size_t)(by + ty + j) * D_ + bx + tx];
    __syncthreads();
#pragma unroll
    for (int j = 0; j < 32; j += 8)
        WhT[(size_t)(bx + ty + j) * D_ + by + tx] = tile[tx][ty + j];
}

// -------- kernel B: fused score[b][s] = sum_e tanh(enc.Wh^T + dec_feat + cov*wc) * v --------
// Block: 256 threads = 2 groups x 128; group g owns rows [g*16, g*16+16), each thread 4 e-cols.
// enc tile (32 rows x 512) resident in LDS (64KB -> 2 blocks/CU); WhT streamed from L2,
// enc read from LDS via broadcast (all lanes same addr -> conflict-free).
#define TM 32
#define TG 16
__global__ __launch_bounds__(256, 2)
void score_kernel(const float* __restrict__ enc, const float* __restrict__ WhT,
                  const float* __restrict__ dec_feat, const float* __restrict__ cov,
                  const float* __restrict__ wc_w, const float* __restrict__ v_w,
                  float* __restrict__ score) {
    int blk = blockIdx.x;             // 0..4095
    int b = blk >> 7;                 // / (S_/TM) = 128
    int s0 = (blk & 127) * TM;
    int t = threadIdx.x;              // 0..255
    int g = t >> 7;                   // group 0/1
    int tg = t & 127;                 // thread-in-group
    int e0 = tg * 4;                  // 4 consecutive e columns

    __shared__ float ldsEnc[TM][D_];  // 64 KB exactly (re-used as reduction buffer later)

    // stage enc tile: one contiguous 64KB chunk, fully coalesced float4 copy
    {
        const float4* src = reinterpret_cast<const float4*>(enc + ((size_t)b * S_ + s0) * D_);
        float4* dst = reinterpret_cast<float4*>(&ldsEnc[0][0]);
#pragma unroll
        for (int i = 0; i < (TM * D_ / 4) / 256; ++i)   // 16 iters
            dst[t + 256 * i] = src[t + 256 * i];
    }
    __syncthreads();

    float acc[TG][4];
#pragma unroll
    for (int r = 0; r < TG; ++r) {
        acc[r][0] = 0.f; acc[r][1] = 0.f; acc[r][2] = 0.f; acc[r][3] = 0.f;
    }

    const float* encRow = &ldsEnc[g * TG][0];

#pragma unroll 2
    for (int kb = 0; kb < D_ / 4; ++kb) {
        int k = kb * 4;
        // 4 rows of WhT (weights for k..k+3, e0..e0+3) — coalesced across lanes
        float4 w0 = *reinterpret_cast<const float4*>(WhT + (size_t)(k + 0) * D_ + e0);
        float4 w1 = *reinterpret_cast<const float4*>(WhT + (size_t)(k + 1) * D_ + e0);
        float4 w2 = *reinterpret_cast<const float4*>(WhT + (size_t)(k + 2) * D_ + e0);
        float4 w3 = *reinterpret_cast<const float4*>(WhT + (size_t)(k + 3) * D_ + e0);
#pragma unroll
        for (int r = 0; r < TG; ++r) {
            float4 a = *reinterpret_cast<const float4*>(&encRow[r * D_ + k]);  // broadcast
            acc[r][0] += a.x * w0.x + a.y * w1.x + a.z * w2.x + a.w * w3.x;
            acc[r][1] += a.x * w0.y + a.y * w1.y + a.z * w2.y + a.w * w3.y;
            acc[r][2] += a.x * w0.z + a.y * w1.z + a.z * w2.z + a.w * w3.z;
            acc[r][3] += a.x * w0.w + a.y * w1.w + a.z * w2.w + a.w * w3.w;
        }
    }

    // epilogue: tanh + v-dot, per-thread partials over its 4 e-cols
    float4 df  = *reinterpret_cast<const float4*>(dec_feat + b * D_ + e0);
    float4 wcv = *reinterpret_cast<const float4*>(wc_w + e0);
    float4 vv  = *reinterpret_cast<const float4*>(v_w + e0);
    float p[TG];
#pragma unroll
    for (int r = 0; r < TG; ++r) {
        float cv = cov[(size_t)b * S_ + s0 + g * TG + r];   // wave-uniform, cached
        float s = 0.f;
        s += fast_tanh(acc[r][0] + df.x + cv * wcv.x) * vv.x;
        s += fast_tanh(acc[r][1] + df.y + cv * wcv.y) * vv.y;
        s += fast_tanh(acc[r][2] + df.z + cv * wcv.z) * vv.z;
        s += fast_tanh(acc[r][3] + df.w + cv * wcv.w) * vv.w;
        p[r] = s;
    }
    // wave-level reduction (64 lanes)
#pragma unroll
    for (int r = 0; r < TG; ++r) {
        float v = p[r];
#pragma unroll
        for (int off = 32; off >= 1; off >>= 1)
            v += __shfl_xor(v, off);
        p[r] = v;
    }
    // cross-wave combine: reuse ldsEnc storage as partial buffer
    __syncthreads();
    float* part = &ldsEnc[0][0];      // [group][wave-in-group][TG]
    int wave = (t >> 6) & 1;
    int lane = t & 63;
    if (lane == 0) {
#pragma unroll
        for (int r = 0; r < TG; ++r)
            part[(g * 2 + wave) * TG + r] = p[r];
    }
    __syncthreads();
    if (t < TM) {
        int gg = t >> 4, r = t & 15;
        score[(size_t)b * S_ + s0 + gg * TG + r] =
            part[(gg * 2 + 0) * TG + r] + part[(gg * 2 + 1) * TG + r];
    }
}

// -------- kernel C1: masked softmax + renorm (== exp*mask / sum), attn & coverage out,
//          also zero the context region (d_out is poisoned with 0xAA before each run)
__global__ __launch_bounds__(1024)
void softmax_kernel(const float* __restrict__ score, const float* __restrict__ mask,
                    const float* __restrict__ cov,
                    float* __restrict__ out_ctx, float* __restrict__ out_attn,
                    float* __restrict__ out_cov) {
    int b = blockIdx.x;
    int t = threadIdx.x;              // 0..1023, each owns 4 s-positions
    __shared__ float red[16];
    float4 sc = reinterpret_cast<const float4*>(score + (size_t)b * S_)[t];
    float4 mk = reinterpret_cast<const float4*>(mask + (size_t)b * S_)[t];

    float m = fmaxf(fmaxf(sc.x, sc.y), fmaxf(sc.z, sc.w));
#pragma unroll
    for (int off = 32; off >= 1; off >>= 1) m = fmaxf(m, __shfl_xor(m, off));
    if ((t & 63) == 0) red[t >> 6] = m;
    __syncthreads();
    float gm = red[0];
#pragma unroll
    for (int i = 1; i < 16; ++i) gm = fmaxf(gm, red[i]);
    __syncthreads();

    float4 w;
    w.x = __expf(sc.x - gm) * mk.x;
    w.y = __expf(sc.y - gm) * mk.y;
    w.z = __expf(sc.z - gm) * mk.z;
    w.w = __expf(sc.w - gm) * mk.w;
    float sum = w.x + w.y + w.z + w.w;
#pragma unroll
    for (int off = 32; off >= 1; off >>= 1) sum += __shfl_xor(sum, off);
    if ((t & 63) == 0) red[t >> 6] = sum;
    __syncthreads();
    float Z = 0.f;
#pragma unroll
    for (int i = 0; i < 16; ++i) Z += red[i];
    float inv = 1.0f / Z;

    float4 at;
    at.x = w.x * inv; at.y = w.y * inv; at.z = w.z * inv; at.w = w.w * inv;
    reinterpret_cast<float4*>(out_attn + (size_t)b * S_)[t] = at;
    float4 cv = reinterpret_cast<const float4*>(cov + (size_t)b * S_)[t];
    float4 cn;
    cn.x = cv.x + at.x; cn.y = cv.y + at.y; cn.z = cv.z + at.z; cn.w = cv.w + at.w;
    reinterpret_cast<float4*>(out_cov + (size_t)b * S_)[t] = cn;

    if (t < D_) out_ctx[b * D_ + t] = 0.0f;
}

// -------- kernel C2: context[b][d] = sum_s attn[b][s] * enc[b][s][d] --------
// grid = 32 b x 16 s-chunks of 256; block 256 threads = 2 s-subgroups x 128 d-quads
__global__ __launch_bounds__(256)
void context_kernel(const float* __restrict__ enc, const float* __restrict__ attn,
                    float* __restrict__ out_ctx) {
    int blk = blockIdx.x;
    int b = blk >> 4;
    int c0 = (blk & 15) * 256;
    int t = threadIdx.x;
    int ssub = t >> 7;                // 0/1
    int dq = t & 127;                 // d quad index
    __shared__ float la[256];
    la[t] = attn[(size_t)b * S_ + c0 + t];
    __syncthreads();
    const float* base = enc + ((size_t)b * S_ + c0) * D_ + dq * 4;
    float4 acc = {0.f, 0.f, 0.f, 0.f};
#pragma unroll 4
    for (int i = 0; i < 128; ++i) {
        int s = 2 * i + ssub;
        float a = la[s];              // broadcast within wave
        float4 ev = *reinterpret_cast<const float4*>(base + (size_t)s * D_);
        acc.x += a * ev.x; acc.y += a * ev.y; acc.z += a * ev.z; acc.w += a * ev.w;
    }
    float* dst = out_ctx + b * D_ + dq * 4;
    atomicAdd(dst + 0, acc.x);
    atomicAdd(dst + 1, acc.y);
    atomicAdd(dst + 2, acc.z);
    atomicAdd(dst + 3, acc.w);
}

extern "C" void kernel_launch(void* const* d_in, const int* in_sizes, int n_in,
                              void* d_out, int out_size, void* d_ws, size_t ws_size,
                              hipStream_t stream) {
    (void)in_sizes; (void)n_in; (void)out_size; (void)ws_size;
    const float* enc   = (const float*)d_in[0];
    const float* h_dec = (const float*)d_in[1];
    const float* c_dec = (const float*)d_in[2];
    const float* mask  = (const float*)d_in[3];
    const float* cov   = (const float*)d_in[4];
    const float* Wh_w  = (const float*)d_in[5];
    const float* Ws_w  = (const float*)d_in[6];
    const float* Ws_b  = (const float*)d_in[7];
    const float* wc_w  = (const float*)d_in[8];
    const float* v_w   = (const float*)d_in[9];

    float* out      = (float*)d_out;
    float* out_ctx  = out;                        // B*D   = 16384
    float* out_attn = out + B_ * D_;              // B*S   = 131072
    float* out_cov  = out + B_ * D_ + B_ * S_;    // B*S   = 131072

    float* ws       = (float*)d_ws;
    float* dec_feat = ws;                         // 16384 floats
    float* WhT      = ws + B_ * D_;               // 262144 floats
    float* score    = ws + B_ * D_ + D_ * D_;     // 131072 floats

    decfeat_kernel<<<B_, 512, 0, stream>>>(h_dec, c_dec, Ws_w, Ws_b, dec_feat);
    transpose_kernel<<<dim3(D_ / 32, D_ / 32), dim3(32, 8), 0, stream>>>(Wh_w, WhT);
    score_kernel<<<B_ * (S_ / TM), 256, 0, stream>>>(enc, WhT, dec_feat, cov, wc_w, v_w, score);
    softmax_kernel<<<B_, 1024, 0, stream>>>(score, mask, cov, out_ctx, out_attn, out_cov);
    context_kernel<<<B_ * 16, 256, 0, stream>>>(enc, out_attn, out_ctx);
}

// Round 2
// 894.648 us; speedup vs baseline: 1.4832x; 1.4832x over previous
//
#include <hip/hip_runtime.h>
#include <hip/hip_bf16.h>

#define B_ 32
#define S_ 4096
#define H_ 256
#define D_ 512

typedef __attribute__((ext_vector_type(8))) short short8v;   // 8 bf16 = 4 VGPR (MFMA A/B frag)
typedef __attribute__((ext_vector_type(4))) float f32x4;     // MFMA C/D frag (16x16)

__device__ __forceinline__ float fast_tanh(float x) {
    return 1.0f - 2.0f / (__expf(2.0f * x) + 1.0f);
}

// round-to-nearest-even fp32 -> bf16 (as ushort); values here are well inside range (no NaN/inf)
__device__ __forceinline__ unsigned short bf_rne(float x) {
    unsigned int u = __float_as_uint(x);
    return (unsigned short)((u + 0x7fffu + ((u >> 16) & 1u)) >> 16);
}
__device__ __forceinline__ float bf_up(unsigned short h) {
    return __uint_as_float(((unsigned int)h) << 16);
}

// -------- kernel A: dec_feat[b][e] = sum_d s_t[b][d] * Ws_w[e][d] + Ws_b[e] --------
__global__ __launch_bounds__(512)
void decfeat_kernel(const float* __restrict__ h_dec, const float* __restrict__ c_dec,
                    const float* __restrict__ Ws_w, const float* __restrict__ Ws_b,
                    float* __restrict__ dec_feat) {
    int b = blockIdx.x;
    int e = threadIdx.x;              // 0..511
    __shared__ float st[D_];
    st[e] = (e < H_) ? h_dec[b * H_ + e] : c_dec[b * H_ + (e - H_)];
    __syncthreads();
    const float4* wr = reinterpret_cast<const float4*>(Ws_w + (size_t)e * D_);
    const float4* sv = reinterpret_cast<const float4*>(st);
    float acc = 0.f;
#pragma unroll 4
    for (int i = 0; i < D_ / 4; ++i) {
        float4 w = wr[i];
        float4 s = sv[i];
        acc += w.x * s.x + w.y * s.y + w.z * s.z + w.w * s.w;
    }
    dec_feat[b * D_ + e] = acc + Ws_b[e];
}

// -------- kernel A2: Wh fp32 [e][k] -> bf16 hi/lo split, same layout (B^T operand) --------
__global__ __launch_bounds__(256)
void wconvert_kernel(const float* __restrict__ Wh, unsigned short* __restrict__ hi,
                     unsigned short* __restrict__ lo) {
    int i = (blockIdx.x * 256 + threadIdx.x) * 4;
    float4 w = *reinterpret_cast<const float4*>(Wh + i);
    ushort4 h, l;
    h.x = bf_rne(w.x); l.x = bf_rne(w.x - bf_up(h.x));
    h.y = bf_rne(w.y); l.y = bf_rne(w.y - bf_up(h.y));
    h.z = bf_rne(w.z); l.z = bf_rne(w.z - bf_up(h.z));
    h.w = bf_rne(w.w); l.w = bf_rne(w.w - bf_up(h.w));
    *reinterpret_cast<ushort4*>(hi + i) = h;
    *reinterpret_cast<ushort4*>(lo + i) = l;
}

// -------- kernel B: fused score via split-bf16 MFMA GEMM + tanh/v-dot epilogue --------
// Block: 256 thr = 4 waves. Tile: BM=32 rows x BN=512 (full width, enc read ONCE).
// Wave w owns cols [w*128, w*128+128) as 8 N-tiles of 16; rows 0..31 as 2 M-tiles.
// A (enc) fp32 -> hi/lo bf16 converted during LDS staging (XOR-swizzled, double-buffered).
// B (WhHi/WhLo) streamed from L2 directly into fragments.
// acc accumulates Ahi*Bhi + Alo*Bhi + Ahi*Blo (lo*lo dropped) -> ~fp32 precision.
#define BM 32
#define BK 64
__global__ __launch_bounds__(256)
void score_kernel(const float* __restrict__ enc, const unsigned short* __restrict__ WhHi,
                  const unsigned short* __restrict__ WhLo, const float* __restrict__ dec_feat,
                  const float* __restrict__ cov, const float* __restrict__ wc_w,
                  const float* __restrict__ v_w, float* __restrict__ score) {
    __shared__ char Ah[2][BM * BK * 2];   // 8 KB per buf, bf16 hi
    __shared__ char Al[2][BM * BK * 2];   // bf16 lo
    __shared__ float covS[BM];
    __shared__ float part[BM * 4];

    const int t = threadIdx.x;
    const int blk = blockIdx.x;           // 0..4095
    const int b = blk >> 7;               // / (S_/BM)
    const int s0 = (blk & 127) * BM;
    const int w = t >> 6;                 // wave 0..3
    const int l = t & 63;
    const int l15 = l & 15;
    const int q = l >> 4;                 // k-quarter / row-group 0..3

    if (t < BM) covS[t] = cov[(size_t)b * S_ + s0 + t];

    // --- staging mapping: thread t loads 8 consecutive fp32 of one enc row ---
    const int srow = t >> 3;              // 0..31
    const int sk = (t & 7) * 8;           // 0..56
    const float* gsrc = enc + ((size_t)(b * S_ + s0 + srow)) * D_ + sk;
    const int swoff = ((srow * BK + sk) * 2) ^ ((srow & 7) << 4);   // swizzled byte offset

    // --- A-fragment read offsets (16x16x32: row = l&15, k = q*8 + j) ---
    const int abase = ((l15 * BK + q * 8) * 2) ^ ((l15 & 7) << 4);  // mt=0; mt=1 adds 16*128

    // --- B-fragment base (col = w*128 + nt*16 + l15, k advances) ---
    const int col0 = w * 128 + l15;
    const unsigned short* bhb = WhHi + ((size_t)col0 << 9) + q * 8;
    const unsigned short* blb = WhLo + ((size_t)col0 << 9) + q * 8;

    f32x4 acc[2][8];
#pragma unroll
    for (int mt = 0; mt < 2; ++mt)
#pragma unroll
        for (int nt = 0; nt < 8; ++nt)
            acc[mt][nt] = (f32x4){0.f, 0.f, 0.f, 0.f};

    float4 r0 = *reinterpret_cast<const float4*>(gsrc);
    float4 r1 = *reinterpret_cast<const float4*>(gsrc + 4);

#pragma unroll 2
    for (int ks = 0; ks < D_ / BK; ++ks) {
        const int cur = ks & 1;
        // convert staged regs -> hi/lo bf16, write to LDS buf[cur]
        {
            float x[8] = {r0.x, r0.y, r0.z, r0.w, r1.x, r1.y, r1.z, r1.w};
            short8v h8, l8;
#pragma unroll
            for (int i = 0; i < 8; ++i) {
                unsigned short h = bf_rne(x[i]);
                h8[i] = (short)h;
                l8[i] = (short)bf_rne(x[i] - bf_up(h));
            }
            *reinterpret_cast<short8v*>(&Ah[cur][swoff]) = h8;
            *reinterpret_cast<short8v*>(&Al[cur][swoff]) = l8;
        }
        // issue next tile's global loads (latency hides under compute)
        if (ks + 1 < D_ / BK) {
            const float* g2 = gsrc + (ks + 1) * BK;
            r0 = *reinterpret_cast<const float4*>(g2);
            r1 = *reinterpret_cast<const float4*>(g2 + 4);
        }
        __syncthreads();

#pragma unroll
        for (int kc = 0; kc < 2; ++kc) {
            const int ao = abase ^ (kc << 6);    // +kc*32 elems (bit 6, disjoint from swizzle path)
            short8v ah0 = *reinterpret_cast<const short8v*>(&Ah[cur][ao]);
            short8v al0 = *reinterpret_cast<const short8v*>(&Al[cur][ao]);
            short8v ah1 = *reinterpret_cast<const short8v*>(&Ah[cur][ao + 16 * 128]);
            short8v al1 = *reinterpret_cast<const short8v*>(&Al[cur][ao + 16 * 128]);
            const unsigned short* bh = bhb + ks * BK + kc * 32;
            const unsigned short* bl = blb + ks * BK + kc * 32;
#pragma unroll
            for (int nt = 0; nt < 8; ++nt) {
                short8v bhv = *reinterpret_cast<const short8v*>(bh + nt * 16 * D_);
                short8v blv = *reinterpret_cast<const short8v*>(bl + nt * 16 * D_);
                acc[0][nt] = __builtin_amdgcn_mfma_f32_16x16x32_bf16(ah0, bhv, acc[0][nt], 0, 0, 0);
                acc[0][nt] = __builtin_amdgcn_mfma_f32_16x16x32_bf16(al0, bhv, acc[0][nt], 0, 0, 0);
                acc[0][nt] = __builtin_amdgcn_mfma_f32_16x16x32_bf16(ah0, blv, acc[0][nt], 0, 0, 0);
                acc[1][nt] = __builtin_amdgcn_mfma_f32_16x16x32_bf16(ah1, bhv, acc[1][nt], 0, 0, 0);
                acc[1][nt] = __builtin_amdgcn_mfma_f32_16x16x32_bf16(al1, bhv, acc[1][nt], 0, 0, 0);
                acc[1][nt] = __builtin_amdgcn_mfma_f32_16x16x32_bf16(ah1, blv, acc[1][nt], 0, 0, 0);
            }
        }
        __syncthreads();
    }

    // --- epilogue: score[s] = sum_e tanh(ef + df_e + cov_s*wc_e) * v_e ---
    float df[8], wcv[8], vv[8];
#pragma unroll
    for (int nt = 0; nt < 8; ++nt) {
        int c = col0 + nt * 16;
        df[nt] = dec_feat[b * D_ + c];
        wcv[nt] = wc_w[c];
        vv[nt] = v_w[c];
    }
    float pr[2][4];
#pragma unroll
    for (int mt = 0; mt < 2; ++mt)
#pragma unroll
        for (int r = 0; r < 4; ++r) {
            float s = 0.f;
            float cvv = covS[mt * 16 + q * 4 + r];
#pragma unroll
            for (int nt = 0; nt < 8; ++nt)
                s += fast_tanh(acc[mt][nt][r] + df[nt] + cvv * wcv[nt]) * vv[nt];
            pr[mt][r] = s;
        }
    // reduce across the 16 lanes (same rows, different cols)
#pragma unroll
    for (int mt = 0; mt < 2; ++mt)
#pragma unroll
        for (int r = 0; r < 4; ++r) {
            float v = pr[mt][r];
#pragma unroll
            for (int off = 8; off >= 1; off >>= 1)
                v += __shfl_xor(v, off);
            pr[mt][r] = v;
        }
    if (l15 == 0) {
#pragma unroll
        for (int mt = 0; mt < 2; ++mt)
#pragma unroll
            for (int r = 0; r < 4; ++r)
                part[(mt * 16 + q * 4 + r) * 4 + w] = pr[mt][r];
    }
    __syncthreads();
    if (t < BM)
        score[(size_t)b * S_ + s0 + t] = part[t * 4] + part[t * 4 + 1] + part[t * 4 + 2] + part[t * 4 + 3];
}

// -------- kernel C1: masked softmax + renorm, attn & coverage out, zero context --------
__global__ __launch_bounds__(1024)
void softmax_kernel(const float* __restrict__ score, const float* __restrict__ mask,
                    const float* __restrict__ cov,
                    float* __restrict__ out_ctx, float* __restrict__ out_attn,
                    float* __restrict__ out_cov) {
    int b = blockIdx.x;
    int t = threadIdx.x;              // 0..1023, each owns 4 s-positions
    __shared__ float red[16];
    float4 sc = reinterpret_cast<const float4*>(score + (size_t)b * S_)[t];
    float4 mk = reinterpret_cast<const float4*>(mask + (size_t)b * S_)[t];

    float m = fmaxf(fmaxf(sc.x, sc.y), fmaxf(sc.z, sc.w));
#pragma unroll
    for (int off = 32; off >= 1; off >>= 1) m = fmaxf(m, __shfl_xor(m, off));
    if ((t & 63) == 0) red[t >> 6] = m;
    __syncthreads();
    float gm = red[0];
#pragma unroll
    for (int i = 1; i < 16; ++i) gm = fmaxf(gm, red[i]);
    __syncthreads();

    float4 wv;
    wv.x = __expf(sc.x - gm) * mk.x;
    wv.y = __expf(sc.y - gm) * mk.y;
    wv.z = __expf(sc.z - gm) * mk.z;
    wv.w = __expf(sc.w - gm) * mk.w;
    float sum = wv.x + wv.y + wv.z + wv.w;
#pragma unroll
    for (int off = 32; off >= 1; off >>= 1) sum += __shfl_xor(sum, off);
    if ((t & 63) == 0) red[t >> 6] = sum;
    __syncthreads();
    float Z = 0.f;
#pragma unroll
    for (int i = 0; i < 16; ++i) Z += red[i];
    float inv = 1.0f / Z;

    float4 at;
    at.x = wv.x * inv; at.y = wv.y * inv; at.z = wv.z * inv; at.w = wv.w * inv;
    reinterpret_cast<float4*>(out_attn + (size_t)b * S_)[t] = at;
    float4 cv = reinterpret_cast<const float4*>(cov + (size_t)b * S_)[t];
    float4 cn;
    cn.x = cv.x + at.x; cn.y = cv.y + at.y; cn.z = cv.z + at.z; cn.w = cv.w + at.w;
    reinterpret_cast<float4*>(out_cov + (size_t)b * S_)[t] = cn;

    if (t < D_) out_ctx[b * D_ + t] = 0.0f;
}

// -------- kernel C2: context[b][d] = sum_s attn[b][s] * enc[b][s][d] --------
__global__ __launch_bounds__(256)
void context_kernel(const float* __restrict__ enc, const float* __restrict__ attn,
                    float* __restrict__ out_ctx) {
    int blk = blockIdx.x;
    int b = blk >> 4;
    int c0 = (blk & 15) * 256;
    int t = threadIdx.x;
    int ssub = t >> 7;                // 0/1
    int dq = t & 127;                 // d quad index
    __shared__ float la[256];
    la[t] = attn[(size_t)b * S_ + c0 + t];
    __syncthreads();
    const float* base = enc + ((size_t)b * S_ + c0) * D_ + dq * 4;
    float4 acc = {0.f, 0.f, 0.f, 0.f};
#pragma unroll 4
    for (int i = 0; i < 128; ++i) {
        int s = 2 * i + ssub;
        float a = la[s];              // broadcast within wave
        float4 ev = *reinterpret_cast<const float4*>(base + (size_t)s * D_);
        acc.x += a * ev.x; acc.y += a * ev.y; acc.z += a * ev.z; acc.w += a * ev.w;
    }
    float* dst = out_ctx + b * D_ + dq * 4;
    atomicAdd(dst + 0, acc.x);
    atomicAdd(dst + 1, acc.y);
    atomicAdd(dst + 2, acc.z);
    atomicAdd(dst + 3, acc.w);
}

extern "C" void kernel_launch(void* const* d_in, const int* in_sizes, int n_in,
                              void* d_out, int out_size, void* d_ws, size_t ws_size,
                              hipStream_t stream) {
    (void)in_sizes; (void)n_in; (void)out_size; (void)ws_size;
    const float* enc   = (const float*)d_in[0];
    const float* h_dec = (const float*)d_in[1];
    const float* c_dec = (const float*)d_in[2];
    const float* mask  = (const float*)d_in[3];
    const float* cov   = (const float*)d_in[4];
    const float* Wh_w  = (const float*)d_in[5];
    const float* Ws_w  = (const float*)d_in[6];
    const float* Ws_b  = (const float*)d_in[7];
    const float* wc_w  = (const float*)d_in[8];
    const float* v_w   = (const float*)d_in[9];

    float* out      = (float*)d_out;
    float* out_ctx  = out;                        // B*D   = 16384
    float* out_attn = out + B_ * D_;              // B*S   = 131072
    float* out_cov  = out + B_ * D_ + B_ * S_;    // B*S   = 131072

    float* ws        = (float*)d_ws;
    float* dec_feat  = ws;                            // 16384 floats
    float* score     = ws + B_ * D_;                  // 131072 floats
    unsigned short* WhHi = (unsigned short*)(ws + B_ * D_ + B_ * S_);   // 512 KB
    unsigned short* WhLo = WhHi + D_ * D_;                              // 512 KB

    decfeat_kernel<<<B_, 512, 0, stream>>>(h_dec, c_dec, Ws_w, Ws_b, dec_feat);
    wconvert_kernel<<<D_ * D_ / 1024, 256, 0, stream>>>(Wh_w, WhHi, WhLo);
    score_kernel<<<B_ * (S_ / BM), 256, 0, stream>>>(enc, WhHi, WhLo, dec_feat, cov, wc_w, v_w, score);
    softmax_kernel<<<B_, 1024, 0, stream>>>(score, mask, cov, out_ctx, out_attn, out_cov);
    context_kernel<<<B_ * 16, 256, 0, stream>>>(enc, out_attn, out_ctx);
}

// Round 3
// 599.220 us; speedup vs baseline: 2.2144x; 1.4930x over previous
//
#include <hip/hip_runtime.h>
#include <hip/hip_bf16.h>

#define B_ 32
#define S_ 4096
#define H_ 256
#define D_ 512

typedef __attribute__((ext_vector_type(8))) short short8v;   // 8 bf16 = 4 VGPR (MFMA A/B frag)
typedef __attribute__((ext_vector_type(4))) float f32x4;     // MFMA C/D frag (16x16)

__device__ __forceinline__ float fast_tanh(float x) {
    return 1.0f - 2.0f / (__expf(2.0f * x) + 1.0f);
}

// round-to-nearest-even fp32 -> bf16 (as ushort); values well inside range (no NaN/inf)
__device__ __forceinline__ unsigned short bf_rne(float x) {
    unsigned int u = __float_as_uint(x);
    return (unsigned short)((u + 0x7fffu + ((u >> 16) & 1u)) >> 16);
}
__device__ __forceinline__ float bf_up(unsigned short h) {
    return __uint_as_float(((unsigned int)h) << 16);
}

// -------- kernel A: dec_feat[b][e] = sum_d s_t[b][d] * Ws_w[e][d] + Ws_b[e] --------
__global__ __launch_bounds__(512)
void decfeat_kernel(const float* __restrict__ h_dec, const float* __restrict__ c_dec,
                    const float* __restrict__ Ws_w, const float* __restrict__ Ws_b,
                    float* __restrict__ dec_feat) {
    int b = blockIdx.x;
    int e = threadIdx.x;              // 0..511
    __shared__ float st[D_];
    st[e] = (e < H_) ? h_dec[b * H_ + e] : c_dec[b * H_ + (e - H_)];
    __syncthreads();
    const float4* wr = reinterpret_cast<const float4*>(Ws_w + (size_t)e * D_);
    const float4* sv = reinterpret_cast<const float4*>(st);
    float acc = 0.f;
#pragma unroll 4
    for (int i = 0; i < D_ / 4; ++i) {
        float4 w = wr[i];
        float4 s = sv[i];
        acc += w.x * s.x + w.y * s.y + w.z * s.z + w.w * s.w;
    }
    dec_feat[b * D_ + e] = acc + Ws_b[e];
}

// -------- kernel A2: Wh -> hi/lo bf16, packed FRAGMENT-MAJOR for coalesced wave loads ----
// packed elem index P = ((ct*16 + k32)*64 + lane)*8 + j, where frag(ct,k32) covers
// cols ct*16..+16, k = k32*32 + (lane>>4)*8 + j. A wave's frag load = 1KB contiguous.
__global__ __launch_bounds__(256)
void wconvert_kernel(const float* __restrict__ Wh, unsigned short* __restrict__ hiP,
                     unsigned short* __restrict__ loP) {
    int p = blockIdx.x * 256 + threadIdx.x;      // 0..32767, one 8-elem j-run each
    int l = p & 63;
    int k32 = (p >> 6) & 15;
    int ct = p >> 10;
    int e = ct * 16 + (l & 15);
    int kbase = k32 * 32 + (l >> 4) * 8;
    const float* src = Wh + (size_t)e * D_ + kbase;
    short8v h8, l8;
#pragma unroll
    for (int j = 0; j < 8; ++j) {
        float w = src[j];
        unsigned short h = bf_rne(w);
        h8[j] = (short)h;
        l8[j] = (short)bf_rne(w - bf_up(h));
    }
    *reinterpret_cast<short8v*>(hiP + (size_t)p * 8) = h8;
    *reinterpret_cast<short8v*>(loP + (size_t)p * 8) = l8;
}

// -------- kernel B: fused score via split-bf16 MFMA, barrier-free K-loop --------
// BM=32 rows, full K=512 staged once (contiguous 64KB) as hi/lo bf16 in LDS
// (XOR swizzle ((row&7)<<4) both sides). 4 waves split N: wave w owns cols
// [w*128, w*128+128) = 8 n-tiles. B hi/lo read from packed layout: each frag load
// is a fully-coalesced 1KB wave read from L2, register double-buffered (depth 1).
#define BM 32
__device__ __forceinline__ void loadB8(short8v (&h)[8], short8v (&l)[8],
                                       const unsigned short* __restrict__ Hi,
                                       const unsigned short* __restrict__ Lo, int off) {
#pragma unroll
    for (int nt = 0; nt < 8; ++nt) {
        h[nt] = *reinterpret_cast<const short8v*>(Hi + off + nt * 8192);
        l[nt] = *reinterpret_cast<const short8v*>(Lo + off + nt * 8192);
    }
}

__global__ __launch_bounds__(256, 2)
void score_kernel(const float* __restrict__ enc, const unsigned short* __restrict__ WhHiP,
                  const unsigned short* __restrict__ WhLoP, const float* __restrict__ dec_feat,
                  const float* __restrict__ cov, const float* __restrict__ wc_w,
                  const float* __restrict__ v_w, float* __restrict__ score) {
    __shared__ alignas(16) char AhB[BM * D_ * 2];   // 32 KB bf16 hi, swizzled
    __shared__ alignas(16) char AlB[BM * D_ * 2];   // 32 KB bf16 lo
    __shared__ float covS[BM];
    __shared__ float part[BM * 4];

    const int t = threadIdx.x;
    const int blk = blockIdx.x;           // 0..4095
    const int b = blk >> 7;               // / (S_/BM)
    const int s0 = (blk & 127) * BM;
    const int w = t >> 6;                 // wave 0..3
    const int l = t & 63;
    const int l15 = l & 15;
    const int q = l >> 4;                 // 0..3
    const int xm = (l15 & 7) << 4;        // swizzle mask

    if (t < BM) covS[t] = cov[(size_t)b * S_ + s0 + t];

    // ---- stage A tile: 32 rows x 512 k = contiguous 64KB; coalesced float4 loads ----
    {
        const float* tile = enc + ((size_t)(b * S_ + s0)) * D_;
        float4 v[16];
#pragma unroll
        for (int i = 0; i < 16; ++i)
            v[i] = *reinterpret_cast<const float4*>(tile + i * 1024 + t * 4);
#pragma unroll
        for (int i = 0; i < 16; ++i) {
            int flat = i * 1024 + t * 4;
            int row = flat >> 9;
            int k = flat & 511;
            ushort4 h4, l4;
            h4.x = bf_rne(v[i].x); l4.x = bf_rne(v[i].x - bf_up(h4.x));
            h4.y = bf_rne(v[i].y); l4.y = bf_rne(v[i].y - bf_up(h4.y));
            h4.z = bf_rne(v[i].z); l4.z = bf_rne(v[i].z - bf_up(h4.z));
            h4.w = bf_rne(v[i].w); l4.w = bf_rne(v[i].w - bf_up(h4.w));
            int hb = (row * 1024 + k * 2) ^ ((row & 7) << 4);
            *reinterpret_cast<ushort4*>(&AhB[hb]) = h4;
            *reinterpret_cast<ushort4*>(&AlB[hb]) = l4;
        }
    }
    __syncthreads();                      // the ONLY pre-epilogue barrier

    f32x4 acc[2][8];
#pragma unroll
    for (int mt = 0; mt < 2; ++mt)
#pragma unroll
        for (int nt = 0; nt < 8; ++nt)
            acc[mt][nt] = (f32x4){0.f, 0.f, 0.f, 0.f};

    const int wbase = w * 65536 + l * 8;  // packed-B elem offset for this lane
    short8v f0h[8], f0l[8], f1h[8], f1l[8];
    loadB8(f0h, f0l, WhHiP, WhLoP, wbase);

#define COMPUTE(kk, bh, bl)                                                             \
    do {                                                                                \
        int ab = (l15 * 1024 + (kk) * 64 + q * 16) ^ xm;                                \
        short8v ah0 = *reinterpret_cast<const short8v*>(&AhB[ab]);                      \
        short8v al0 = *reinterpret_cast<const short8v*>(&AlB[ab]);                      \
        short8v ah1 = *reinterpret_cast<const short8v*>(&AhB[ab + 16 * 1024]);          \
        short8v al1 = *reinterpret_cast<const short8v*>(&AlB[ab + 16 * 1024]);          \
        _Pragma("unroll")                                                               \
        for (int nt = 0; nt < 8; ++nt) {                                                \
            acc[0][nt] = __builtin_amdgcn_mfma_f32_16x16x32_bf16(ah0, bh[nt], acc[0][nt], 0, 0, 0); \
            acc[0][nt] = __builtin_amdgcn_mfma_f32_16x16x32_bf16(al0, bh[nt], acc[0][nt], 0, 0, 0); \
            acc[0][nt] = __builtin_amdgcn_mfma_f32_16x16x32_bf16(ah0, bl[nt], acc[0][nt], 0, 0, 0); \
            acc[1][nt] = __builtin_amdgcn_mfma_f32_16x16x32_bf16(ah1, bh[nt], acc[1][nt], 0, 0, 0); \
            acc[1][nt] = __builtin_amdgcn_mfma_f32_16x16x32_bf16(al1, bh[nt], acc[1][nt], 0, 0, 0); \
            acc[1][nt] = __builtin_amdgcn_mfma_f32_16x16x32_bf16(ah1, bl[nt], acc[1][nt], 0, 0, 0); \
        }                                                                               \
    } while (0)

    for (int kk = 0; kk < 16; kk += 2) {
        loadB8(f1h, f1l, WhHiP, WhLoP, wbase + (kk + 1) * 512);
        COMPUTE(kk, f0h, f0l);
        if (kk + 2 < 16) loadB8(f0h, f0l, WhHiP, WhLoP, wbase + (kk + 2) * 512);
        COMPUTE(kk + 1, f1h, f1l);
    }
#undef COMPUTE

    // ---- epilogue: score[s] = sum_e tanh(ef + df_e + cov_s*wc_e) * v_e ----
    const int col0 = w * 128 + l15;
    float df[8], wcv[8], vv[8];
#pragma unroll
    for (int nt = 0; nt < 8; ++nt) {
        int c = col0 + nt * 16;
        df[nt] = dec_feat[b * D_ + c];
        wcv[nt] = wc_w[c];
        vv[nt] = v_w[c];
    }
    float pr[2][4];
#pragma unroll
    for (int mt = 0; mt < 2; ++mt)
#pragma unroll
        for (int r = 0; r < 4; ++r) {
            float s = 0.f;
            float cvv = covS[mt * 16 + q * 4 + r];
#pragma unroll
            for (int nt = 0; nt < 8; ++nt)
                s += fast_tanh(acc[mt][nt][r] + df[nt] + cvv * wcv[nt]) * vv[nt];
            pr[mt][r] = s;
        }
#pragma unroll
    for (int mt = 0; mt < 2; ++mt)
#pragma unroll
        for (int r = 0; r < 4; ++r) {
            float v = pr[mt][r];
#pragma unroll
            for (int off = 8; off >= 1; off >>= 1)
                v += __shfl_xor(v, off);
            pr[mt][r] = v;
        }
    if (l15 == 0) {
#pragma unroll
        for (int mt = 0; mt < 2; ++mt)
#pragma unroll
            for (int r = 0; r < 4; ++r)
                part[(mt * 16 + q * 4 + r) * 4 + w] = pr[mt][r];
    }
    __syncthreads();
    if (t < BM)
        score[(size_t)b * S_ + s0 + t] = part[t * 4] + part[t * 4 + 1] + part[t * 4 + 2] + part[t * 4 + 3];
}

// -------- kernel C1: masked softmax + renorm, attn & coverage out, zero context --------
__global__ __launch_bounds__(1024)
void softmax_kernel(const float* __restrict__ score, const float* __restrict__ mask,
                    const float* __restrict__ cov,
                    float* __restrict__ out_ctx, float* __restrict__ out_attn,
                    float* __restrict__ out_cov) {
    int b = blockIdx.x;
    int t = threadIdx.x;              // 0..1023, each owns 4 s-positions
    __shared__ float red[16];
    float4 sc = reinterpret_cast<const float4*>(score + (size_t)b * S_)[t];
    float4 mk = reinterpret_cast<const float4*>(mask + (size_t)b * S_)[t];

    float m = fmaxf(fmaxf(sc.x, sc.y), fmaxf(sc.z, sc.w));
#pragma unroll
    for (int off = 32; off >= 1; off >>= 1) m = fmaxf(m, __shfl_xor(m, off));
    if ((t & 63) == 0) red[t >> 6] = m;
    __syncthreads();
    float gm = red[0];
#pragma unroll
    for (int i = 1; i < 16; ++i) gm = fmaxf(gm, red[i]);
    __syncthreads();

    float4 wv;
    wv.x = __expf(sc.x - gm) * mk.x;
    wv.y = __expf(sc.y - gm) * mk.y;
    wv.z = __expf(sc.z - gm) * mk.z;
    wv.w = __expf(sc.w - gm) * mk.w;
    float sum = wv.x + wv.y + wv.z + wv.w;
#pragma unroll
    for (int off = 32; off >= 1; off >>= 1) sum += __shfl_xor(sum, off);
    if ((t & 63) == 0) red[t >> 6] = sum;
    __syncthreads();
    float Z = 0.f;
#pragma unroll
    for (int i = 0; i < 16; ++i) Z += red[i];
    float inv = 1.0f / Z;

    float4 at;
    at.x = wv.x * inv; at.y = wv.y * inv; at.z = wv.z * inv; at.w = wv.w * inv;
    reinterpret_cast<float4*>(out_attn + (size_t)b * S_)[t] = at;
    float4 cv = reinterpret_cast<const float4*>(cov + (size_t)b * S_)[t];
    float4 cn;
    cn.x = cv.x + at.x; cn.y = cv.y + at.y; cn.z = cv.z + at.z; cn.w = cv.w + at.w;
    reinterpret_cast<float4*>(out_cov + (size_t)b * S_)[t] = cn;

    if (t < D_) out_ctx[b * D_ + t] = 0.0f;
}

// -------- kernel C2: context[b][d] = sum_s attn[b][s] * enc[b][s][d] --------
// 512 blocks x 512 thr (8 waves) -> 2 blocks/CU, 16 waves/CU for streaming BW
__global__ __launch_bounds__(512)
void context_kernel(const float* __restrict__ enc, const float* __restrict__ attn,
                    float* __restrict__ out_ctx) {
    int blk = blockIdx.x;
    int b = blk >> 4;
    int c0 = (blk & 15) * 256;
    int t = threadIdx.x;
    int ssub = t >> 7;                // 0..3
    int dq = t & 127;                 // d quad index
    __shared__ float la[256];
    if (t < 256) la[t] = attn[(size_t)b * S_ + c0 + t];
    __syncthreads();
    const float* base = enc + ((size_t)b * S_ + c0) * D_ + dq * 4;
    float4 acc = {0.f, 0.f, 0.f, 0.f};
#pragma unroll 4
    for (int i = 0; i < 64; ++i) {
        int s = 4 * i + ssub;
        float a = la[s];              // broadcast within wave
        float4 ev = *reinterpret_cast<const float4*>(base + (size_t)s * D_);
        acc.x += a * ev.x; acc.y += a * ev.y; acc.z += a * ev.z; acc.w += a * ev.w;
    }
    float* dst = out_ctx + b * D_ + dq * 4;
    atomicAdd(dst + 0, acc.x);
    atomicAdd(dst + 1, acc.y);
    atomicAdd(dst + 2, acc.z);
    atomicAdd(dst + 3, acc.w);
}

extern "C" void kernel_launch(void* const* d_in, const int* in_sizes, int n_in,
                              void* d_out, int out_size, void* d_ws, size_t ws_size,
                              hipStream_t stream) {
    (void)in_sizes; (void)n_in; (void)out_size; (void)ws_size;
    const float* enc   = (const float*)d_in[0];
    const float* h_dec = (const float*)d_in[1];
    const float* c_dec = (const float*)d_in[2];
    const float* mask  = (const float*)d_in[3];
    const float* cov   = (const float*)d_in[4];
    const float* Wh_w  = (const float*)d_in[5];
    const float* Ws_w  = (const float*)d_in[6];
    const float* Ws_b  = (const float*)d_in[7];
    const float* wc_w  = (const float*)d_in[8];
    const float* v_w   = (const float*)d_in[9];

    float* out      = (float*)d_out;
    float* out_ctx  = out;                        // B*D   = 16384
    float* out_attn = out + B_ * D_;              // B*S   = 131072
    float* out_cov  = out + B_ * D_ + B_ * S_;    // B*S   = 131072

    float* ws        = (float*)d_ws;
    float* dec_feat  = ws;                            // 16384 floats
    float* score     = ws + B_ * D_;                  // 131072 floats
    unsigned short* WhHiP = (unsigned short*)(ws + B_ * D_ + B_ * S_);  // 512 KB packed
    unsigned short* WhLoP = WhHiP + D_ * D_;                            // 512 KB packed

    decfeat_kernel<<<B_, 512, 0, stream>>>(h_dec, c_dec, Ws_w, Ws_b, dec_feat);
    wconvert_kernel<<<D_ * D_ / (256 * 8), 256, 0, stream>>>(Wh_w, WhHiP, WhLoP);
    score_kernel<<<B_ * (S_ / BM), 256, 0, stream>>>(enc, WhHiP, WhLoP, dec_feat, cov, wc_w, v_w, score);
    softmax_kernel<<<B_, 1024, 0, stream>>>(score, mask, cov, out_ctx, out_attn, out_cov);
    context_kernel<<<B_ * 16, 512, 0, stream>>>(enc, out_attn, out_ctx);
}